// Round 3
// baseline (1365.737 us; speedup 1.0000x reference)
//
#include <hip/hip_runtime.h>
#include <stdint.h>

typedef __attribute__((ext_vector_type(8))) short short8;
typedef __attribute__((ext_vector_type(4))) float f32x4;
typedef __attribute__((ext_vector_type(4))) unsigned int u32x4;

__device__ __forceinline__ float bf2f(unsigned short u){
  union { unsigned int i; float f; } x; x.i = ((unsigned int)u) << 16; return x.f;
}
__device__ __forceinline__ unsigned short f2bf(float f){
  union { float f; unsigned int i; } x; x.f = f;
  unsigned int r = x.i + 0x7fffu + ((x.i >> 16) & 1u);
  return (unsigned short)(r >> 16);
}

// ---------------- hypernet: wa[l][b][k] = y[b]·fc_w[l][k] + fc_b[l][k] ----------------
__global__ void wa_kernel(const float* __restrict__ y, const float* __restrict__ fcw,
                          const float* __restrict__ fcb, float* __restrict__ wa){
  int l = blockIdx.x >> 3, b = blockIdx.x & 7;
  int k = threadIdx.x;
  if (k >= 100) return;
  const float* yr = y + b*512;
  const float* wr = fcw + (l*100 + k)*512;
  float s = 0.f;
  for (int j=0;j<512;j++) s += yr[j]*wr[j];
  wa[(l*8+b)*100 + k] = s + fcb[l*100 + k];
}

// ---------------- cast WB -> bf16, rows padded to Mpad, K padded to 128 ----------------
__global__ void wbh_kernel(const float* __restrict__ wb, unsigned short* __restrict__ o,
                           int M3, int Mpad){
  int idx = blockIdx.x*256 + threadIdx.x;
  if (idx >= Mpad*128) return;
  int row = idx >> 7, k = idx & 127;
  float v = (row < M3 && k < 100) ? wb[row*100 + k] : 0.f;
  o[idx] = f2bf(v);
}

// ---------------- wach[b][i][k] = wa[b][k] * WC[i][k], K padded to 128 ----------------
__global__ void wach_kernel(const float* __restrict__ wc, const float* __restrict__ wa_l,
                            unsigned short* __restrict__ o, int N3){
  int idx = blockIdx.x*256 + threadIdx.x;
  if (idx >= 8*N3*128) return;
  int k = idx & 127; int bi = idx >> 7;
  int i = bi % N3, b = bi / N3;
  float v = (k < 100) ? wa_l[b*100 + k] * wc[i*100 + k] : 0.f;
  o[idx] = f2bf(v);
}

// ---------------- weight-gen GEMM: wboi[b][o][i] = WBh[o] · wach[b][i]  (K=128 padded) --
__global__ __launch_bounds__(256) void wgen_kernel(
    const unsigned short* __restrict__ wbh, const unsigned short* __restrict__ wach,
    unsigned short* __restrict__ wboi, int M3, int N3){
  __shared__ unsigned short At[128*136];
  __shared__ unsigned short Bt[128*136];
  const int m0 = blockIdx.x*128, n0 = blockIdx.y*128, b = blockIdx.z;
  const int t = threadIdx.x;
  const unsigned short* As = wbh + (size_t)m0*128;
  const unsigned short* Bs = wach + ((size_t)b*N3 + n0)*128;
  #pragma unroll
  for (int j=0;j<8;j++){
    int c = j*256 + t;
    int row = c >> 4, q = c & 15;
    *(u32x4*)&At[row*136 + q*8] = *(const u32x4*)&As[row*128 + q*8];
    *(u32x4*)&Bt[row*136 + q*8] = *(const u32x4*)&Bs[row*128 + q*8];
  }
  __syncthreads();
  const int wv = t >> 6, lane = t & 63;
  const int wm = (wv >> 1)*64, wn = (wv & 1)*64;
  const int lr = lane & 15, lkg = lane >> 4, lk8 = lkg*8;
  f32x4 acc[4][4];
  #pragma unroll
  for (int i=0;i<4;i++) for (int j=0;j<4;j++) acc[i][j] = (f32x4){0,0,0,0};
  #pragma unroll
  for (int kc=0;kc<4;kc++){
    short8 a[4], bv[4];
    #pragma unroll
    for (int mi=0;mi<4;mi++) a[mi] = *(const short8*)&At[(wm+mi*16+lr)*136 + kc*32 + lk8];
    #pragma unroll
    for (int ni=0;ni<4;ni++) bv[ni] = *(const short8*)&Bt[(wn+ni*16+lr)*136 + kc*32 + lk8];
    #pragma unroll
    for (int mi=0;mi<4;mi++)
      #pragma unroll
      for (int ni=0;ni<4;ni++)
        acc[mi][ni] = __builtin_amdgcn_mfma_f32_16x16x32_bf16(a[mi], bv[ni], acc[mi][ni], 0,0,0);
  }
  #pragma unroll
  for (int mi=0;mi<4;mi++)
    #pragma unroll
    for (int ni=0;ni<4;ni++)
      #pragma unroll
      for (int r=0;r<4;r++){
        int o = m0 + wm + mi*16 + lkg*4 + r;
        int i = n0 + wn + ni*16 + lr;
        if (o < M3) wboi[((size_t)b*M3 + o)*N3 + i] = f2bf(acc[mi][ni][r]);
      }
}

// ---------------- weight transpose: W2[b][tap][co][ci] = wboi[b][3co+t/(3cin)][t%(3cin)],
//                  t = ci*9+tap. (contiguous per (b,co): offset t) ----------------
__global__ void wtr_kernel(const unsigned short* __restrict__ wboi, unsigned short* __restrict__ W2,
                           int CIN, int COUT){
  __shared__ unsigned short buf[9*512];
  const int bid = blockIdx.x;
  const int co = bid % COUT, b = bid / COUT;
  const int t = threadIdx.x;
  const int n = 9*CIN;
  const unsigned short* src = wboi + ((size_t)b*3*COUT + 3*co)*(size_t)(3*CIN);
  for (int i = t; i < n; i += 256) buf[i] = src[i];
  __syncthreads();
  for (int tap=0; tap<9; ++tap){
    unsigned short* dst = W2 + (((size_t)(b*9 + tap)*COUT) + co)*CIN;
    for (int ci = t; ci < CIN; ci += 256) dst[ci] = buf[ci*9 + tap];
  }
}

// ---------------- cast x (NCHW f32) -> padded NHWC bf16 [8][68][68][512] ----------------
__global__ void castx_kernel(const float* __restrict__ x, unsigned short* __restrict__ act){
  __shared__ float tile[64][65];
  int bid = blockIdx.x;
  int ct = bid & 7; int hp = (bid >> 3) % 68; int b = bid / 544;
  int c0 = ct * 64;
  int t = threadIdx.x;
  unsigned short* orow = act + ((size_t)(b*68 + hp)*68)*512;
  if (hp < 2 || hp >= 66){
    for (int idx = t; idx < 68*64; idx += 256){
      int wp = idx >> 6, c = idx & 63;
      orow[wp*512 + c0 + c] = 0;
    }
    return;
  }
  int h = hp - 2;
  for (int idx = t; idx < 64*64; idx += 256){
    int r = idx >> 6, w = idx & 63;
    tile[r][w] = x[((size_t)(b*512 + c0 + r)*64 + h)*64 + w];
  }
  __syncthreads();
  for (int idx = t; idx < 68*64; idx += 256){
    int wp = idx >> 6, c = idx & 63;
    float v = (wp < 2 || wp >= 66) ? 0.f : tile[c][wp-2];
    orow[wp*512 + c0 + c] = f2bf(v);
  }
}

// ---------------- conv: implicit GEMM, M=64co x N=256px(16x16) tile, K-step 32ci x 9 taps
template<int CIN, int COUT>
__global__ __launch_bounds__(256, 2) void conv_kernel(
    const unsigned short* __restrict__ act, const unsigned short* __restrict__ W2,
    float* __restrict__ cbuf){
  __shared__ unsigned short Al[9*64*40];   // [tap][co][ci(32, pad40)]
  __shared__ unsigned short Pl[20*20*40];  // [ph][pw][ci(32, pad40)]
  const int co0 = blockIdx.x * 64;
  const int h0 = (blockIdx.y >> 2) * 16;
  const int w0 = (blockIdx.y & 3) * 16;
  const int b = blockIdx.z;
  const int t = threadIdx.x;
  const int wv = t >> 6, lane = t & 63;
  const int lr = lane & 15, lkg = lane >> 4, lk8 = lkg*8;

  const unsigned short* actb = act + (size_t)b*68*68*CIN;
  const unsigned short* wb = W2 + (size_t)b*9*COUT*CIN;

  f32x4 acc[4][4];
  #pragma unroll
  for (int i=0;i<4;i++) for (int j=0;j<4;j++) acc[i][j] = (f32x4){0,0,0,0};

  for (int cs = 0; cs < CIN/32; ++cs){
    const int cb = cs*32;
    #pragma unroll
    for (int j=0;j<9;j++){                    // A: 9*64*32 = 2304 16B-chunks
      int c = j*256 + t;
      int tap = c >> 8, rem = c & 255;
      int co = rem >> 2, q = rem & 3;
      u32x4 v = *(const u32x4*)&wb[((size_t)(tap*COUT + co0 + co))*CIN + cb + q*8];
      *(u32x4*)&Al[(tap*64 + co)*40 + q*8] = v;
    }
    #pragma unroll
    for (int j=0;j<7;j++){                    // patch: 20*20*32 = 1600 16B-chunks
      int c = j*256 + t;
      if (c < 1600){
        int ph = c/80, rem = c%80, pw = rem>>2, q = rem&3;
        u32x4 v = *(const u32x4*)&actb[(size_t)((h0+ph)*68 + (w0+pw))*CIN + cb + q*8];
        *(u32x4*)&Pl[(ph*20+pw)*40 + q*8] = v;
      }
    }
    __syncthreads();
    #pragma unroll
    for (int kh=0;kh<3;kh++){
      #pragma unroll
      for (int kw=0;kw<3;kw++){
        const int tap = kh*3 + kw;
        short8 a[4], bv[4];
        #pragma unroll
        for (int mi=0;mi<4;mi++)
          a[mi] = *(const short8*)&Al[(tap*64 + mi*16 + lr)*40 + lk8];
        #pragma unroll
        for (int ni=0;ni<4;ni++){
          int pr = wv*4 + ni + 2*kh;
          int pc = lr + 2*kw;
          bv[ni] = *(const short8*)&Pl[(pr*20 + pc)*40 + lk8];
        }
        #pragma unroll
        for (int mi=0;mi<4;mi++)
          #pragma unroll
          for (int ni=0;ni<4;ni++)
            acc[mi][ni] = __builtin_amdgcn_mfma_f32_16x16x32_bf16(a[mi], bv[ni], acc[mi][ni], 0,0,0);
      }
    }
    __syncthreads();
  }
  float* ob = cbuf + (size_t)b*64*64*COUT;
  #pragma unroll
  for (int mi=0;mi<4;mi++){
    int co = co0 + mi*16 + lkg*4;
    #pragma unroll
    for (int ni=0;ni<4;ni++){
      int hh = h0 + wv*4 + ni;
      int ww = w0 + lr;
      *(f32x4*)&ob[(size_t)(hh*64 + ww)*COUT + co] = acc[mi][ni];
    }
  }
}

// ---------------- BN stats (atomics) ----------------
__global__ void bnstat_kernel(const float* __restrict__ cbuf, float* __restrict__ bnacc, int C){
  const int t = threadIdx.x;
  const size_t p0 = (size_t)blockIdx.x * 64;
  float s0=0.f, q0=0.f, s1=0.f, q1=0.f;
  const int c1 = t + 256;
  for (int pi=0; pi<64; ++pi){
    const float* row = cbuf + (p0 + pi)*C;
    if (t < C){ float v = row[t]; s0 += v; q0 += v*v; }
    if (c1 < C){ float v = row[c1]; s1 += v; q1 += v*v; }
  }
  if (t < C){ atomicAdd(&bnacc[t], s0); atomicAdd(&bnacc[C+t], q0); }
  if (c1 < C){ atomicAdd(&bnacc[c1], s1); atomicAdd(&bnacc[C+c1], q1); }
}

__global__ void bnfin_kernel(const float* __restrict__ bnacc, float* __restrict__ bnmr, int C){
  int c = blockIdx.x*256 + threadIdx.x;
  if (c >= C) return;
  const float n = 8.f*64.f*64.f;
  float mean = bnacc[c]/n;
  float var = bnacc[C+c]/n - mean*mean;
  bnmr[c] = mean;
  bnmr[C+c] = rsqrtf(var + 1e-5f);
}

// ---------------- BN apply + ReLU + bf16 cast into padded NHWC (writes border zeros) ----
__global__ void bnapply_kernel(const float* __restrict__ cbuf, const float* __restrict__ bnmr,
                               unsigned short* __restrict__ actout, int lc){
  const int C = 1 << lc;
  const int bid = blockIdx.x;
  const int hp = bid % 68, b = bid / 68;
  const int t = threadIdx.x;
  unsigned short* orow = actout + (((size_t)(b*68 + hp))*68 << lc);
  const bool hb = (hp < 2) || (hp >= 66);
  const int n = 68 << lc;
  for (int idx = t; idx < n; idx += 256){
    int wp = idx >> lc, c = idx & (C-1);
    float v = 0.f;
    if (!hb && wp >= 2 && wp < 66){
      float xx = cbuf[((((size_t)b*64 + (hp-2))*64 + (wp-2)) << lc) + c];
      float z = (xx - bnmr[c]) * bnmr[C + c];
      v = z > 0.f ? z : 0.f;
    }
    orow[idx] = f2bf(v);
  }
}

// ---------------- 1x1 output conv (64 -> 1) ----------------
__global__ void conv1x1_kernel(const unsigned short* __restrict__ act, const float* __restrict__ ow,
                               const float* __restrict__ ob, float* __restrict__ out64){
  int idx = blockIdx.x*256 + threadIdx.x;
  int b = idx >> 12, p = idx & 4095;
  int h = p >> 6, w = p & 63;
  const unsigned short* ar = act + (((size_t)(b*68 + h+2))*68 + (w+2))*64;
  float s = 0.f;
  #pragma unroll
  for (int c=0;c<64;c++) s += bf2f(ar[c]) * ow[c];
  out64[idx] = s + ob[0];
}

// ---------------- 8x nearest upsample ----------------
__global__ void upsample_kernel(const float* __restrict__ out64, float* __restrict__ o){
  int idx = blockIdx.x*256 + threadIdx.x;
  int b = idx >> 18, r = idx & 262143;
  int hh = r >> 9, ww = r & 511;
  o[idx] = out64[(b << 12) + ((hh >> 3) << 6) + (ww >> 3)];
}

extern "C" void kernel_launch(void* const* d_in, const int* in_sizes, int n_in,
                              void* d_out, int out_size, void* d_ws, size_t ws_size,
                              hipStream_t stream){
  const float* x   = (const float*)d_in[0];
  const float* y   = (const float*)d_in[1];
  const float* fcw = (const float*)d_in[2];
  const float* fcb = (const float*)d_in[3];
  const float* wbp[6]; const float* wcp[6];
  // setup_inputs dict order interleaves wb/wc; reference signature groups them.
  // Disambiguate via in_sizes[10]: dict order -> wb3 (768*100=76800); sig order -> wc0 (153600).
  bool dictOrder = (in_sizes[10] == 76800);
  for (int i=0;i<6;i++){
    if (dictOrder){ wbp[i] = (const float*)d_in[4+2*i]; wcp[i] = (const float*)d_in[5+2*i]; }
    else          { wbp[i] = (const float*)d_in[4+i];   wcp[i] = (const float*)d_in[10+i]; }
  }
  const float* ow  = (const float*)d_in[16];
  const float* obp = (const float*)d_in[17];
  float* out = (float*)d_out;

  static const int CIN[6]  = {512,512,512,512,256,128};
  static const int COUT[6] = {512,512,512,256,128,64};
  static const int MPAD[6] = {1536,1536,1536,768,384,256};
  static const int LC[6]   = {9,9,9,8,7,6};

  char* ws = (char*)d_ws; size_t off = 0;
  auto alloc = [&](size_t bytes)->void*{ void* p = ws + off; off += (bytes + 255) & ~(size_t)255; return p; };
  unsigned short* actA = (unsigned short*)alloc((size_t)8*68*68*512*2);
  unsigned short* actB = (unsigned short*)alloc((size_t)8*68*68*512*2);
  float* cbuf = (float*)alloc((size_t)8*64*64*512*4);      // 64MB; also aliases wboi (37.75MB)
  unsigned short* wboi = (unsigned short*)cbuf;            // dead before conv writes cbuf
  unsigned short* W2 = (unsigned short*)alloc((size_t)8*9*512*512*2);
  float* wa = (float*)alloc(6*8*100*4);
  unsigned short* wbh = (unsigned short*)alloc((size_t)6016*128*2);
  unsigned short* wach = (unsigned short*)alloc((size_t)58368*128*2);
  float* bnacc = (float*)alloc(1024*4);
  float* bnmr  = (float*)alloc(1024*4);
  float* out64 = (float*)alloc(8*4096*4);

  wa_kernel<<<48, 128, 0, stream>>>(y, fcw, fcb, wa);
  const unsigned short* wbhp[6]; const unsigned short* wachp[6];
  { int mo = 0, co = 0;
    for (int l=0;l<6;l++){
      int M3 = 3*COUT[l], N3 = 3*CIN[l];
      unsigned short* wb_l = wbh + (size_t)mo*128;
      unsigned short* wc_l = wach + (size_t)co*128;
      wbh_kernel<<<MPAD[l]*128/256, 256, 0, stream>>>(wbp[l], wb_l, M3, MPAD[l]);
      wach_kernel<<<8*N3*128/256, 256, 0, stream>>>(wcp[l], wa + l*800, wc_l, N3);
      wbhp[l] = wb_l; wachp[l] = wc_l;
      mo += MPAD[l]; co += 8*N3;
    }
  }
  castx_kernel<<<8*68*8, 256, 0, stream>>>(x, actA);

  unsigned short* ain = actA; unsigned short* aout = actB;
  for (int l=0;l<6;l++){
    int M3 = 3*COUT[l], N3 = 3*CIN[l];
    wgen_kernel<<<dim3(MPAD[l]/128, N3/128, 8), 256, 0, stream>>>(wbhp[l], wachp[l], wboi, M3, N3);
    wtr_kernel<<<8*COUT[l], 256, 0, stream>>>(wboi, W2, CIN[l], COUT[l]);
    switch(l){
      case 0: case 1: case 2:
        conv_kernel<512,512><<<dim3(8,16,8),256,0,stream>>>(ain, W2, cbuf); break;
      case 3:
        conv_kernel<512,256><<<dim3(4,16,8),256,0,stream>>>(ain, W2, cbuf); break;
      case 4:
        conv_kernel<256,128><<<dim3(2,16,8),256,0,stream>>>(ain, W2, cbuf); break;
      case 5:
        conv_kernel<128,64><<<dim3(1,16,8),256,0,stream>>>(ain, W2, cbuf); break;
    }
    hipMemsetAsync(bnacc, 0, 2*COUT[l]*sizeof(float), stream);
    bnstat_kernel<<<512, 256, 0, stream>>>(cbuf, bnacc, COUT[l]);
    bnfin_kernel<<<2, 256, 0, stream>>>(bnacc, bnmr, COUT[l]);
    bnapply_kernel<<<8*68, 256, 0, stream>>>(cbuf, bnmr, aout, LC[l]);
    unsigned short* tmp = ain; ain = aout; aout = tmp;
  }
  conv1x1_kernel<<<(8*4096)/256, 256, 0, stream>>>(ain, ow, obp, out64);
  upsample_kernel<<<(8*512*512)/256, 256, 0, stream>>>(out64, out);
}